// Round 1
// 349.338 us; speedup vs baseline: 1.2560x; 1.2560x over previous
//
#include <hip/hip_runtime.h>
#include <cstdint>
#include <cmath>
#include <cstring>
#include <mutex>

// ============================================================================
// Host-side replication of numpy default_rng(42) -> CG coefficient table.
// (verified passing: absmax 0.031)
// ============================================================================
namespace nprng {

typedef unsigned __int128 u128;

struct PCG64 {
  u128 state, inc;
  static inline u128 mult() {
    return ((u128)0x2360ED051FC65DA4ULL << 64) | 0x4385DF649FCCF645ULL;
  }
  inline void step() { state = state * mult() + inc; }
  inline uint64_t next() {
    step();
    uint64_t hi = (uint64_t)(state >> 64), lo = (uint64_t)state;
    uint64_t x = hi ^ lo;
    unsigned rot = (unsigned)(state >> 122);
    return (x >> rot) | (x << ((64u - rot) & 63u));
  }
  void srandom(u128 initstate, u128 initseq) {
    state = 0;
    inc = (initseq << 1) | 1;
    step();
    state += initstate;
    step();
  }
};

static void seed_sequence_42_raw(uint32_t st[8]) {
  uint32_t pool[4];
  uint32_t hash_const = 0x43b0d7e5u;  // INIT_A
  auto hashmix = [&hash_const](uint32_t v) -> uint32_t {
    v ^= hash_const;
    hash_const *= 0x931e8875u;  // MULT_A
    v *= hash_const;
    v ^= v >> 16;
    return v;
  };
  auto mix = [](uint32_t x, uint32_t y) -> uint32_t {
    uint32_t r = 0xca01f9ddu * x - 0x4973f715u * y;  // MULT_L*x - MULT_R*y
    r ^= r >> 16;
    return r;
  };
  pool[0] = hashmix(42u);
  for (int i = 1; i < 4; ++i) pool[i] = hashmix(0u);
  for (int s = 0; s < 4; ++s)
    for (int d = 0; d < 4; ++d)
      if (s != d) pool[d] = mix(pool[d], hashmix(pool[s]));
  uint32_t gen_const = 0x8b51f9ddu;  // INIT_B
  for (int i = 0; i < 8; ++i) {
    uint32_t v = pool[i & 3];
    v ^= gen_const;
    gen_const *= 0x58f38dedu;  // MULT_B
    v *= gen_const;
    v ^= v >> 16;
    st[i] = v;
  }
}

static inline double next_uniform(PCG64& g) {
  return (double)(g.next() >> 11) * (1.0 / 9007199254740992.0);
}

static void make_gen(PCG64& g) {
  uint32_t st[8];
  seed_sequence_42_raw(st);
  const double target = 0.7739560485559633;
  for (int pairing = 0; pairing < 2; ++pairing) {
    uint64_t s[4];
    for (int i = 0; i < 4; ++i)
      s[i] = pairing == 0
                 ? ((uint64_t)st[2 * i] | ((uint64_t)st[2 * i + 1] << 32))
                 : (((uint64_t)st[2 * i] << 32) | (uint64_t)st[2 * i + 1]);
    for (int so = 0; so < 2; ++so) {
      PCG64 t;
      if (so == 0)
        t.srandom(((u128)s[0] << 64) | s[1], ((u128)s[2] << 64) | s[3]);
      else
        t.srandom(((u128)s[1] << 64) | s[0], ((u128)s[3] << 64) | s[2]);
      PCG64 probe = t;
      if (fabs(next_uniform(probe) - target) < 1e-13) {
        g = t;
        return;
      }
    }
  }
  uint64_t s[4];
  for (int i = 0; i < 4; ++i)
    s[i] = (uint64_t)st[2 * i] | ((uint64_t)st[2 * i + 1] << 32);
  g.srandom(((u128)s[0] << 64) | s[1], ((u128)s[2] << 64) | s[3]);
}

struct Zig {
  double wi[256], fi[256];
  uint64_t ki[256];
};

static void build_zig(Zig& z) {
  const long double R = 3.6541528853610087963519472518L;
  const long double T52 = 4503599627370496.0L;  // 2^52
  long double f255 = expl(-0.5L * R * R);
  long double v =
      R * f255 +
      sqrtl(1.57079632679489661923132169163975144L) *
          erfcl(R / 1.41421356237309504880168872420969808L);
  long double x[256], fi[256];
  x[255] = R;
  fi[255] = f255;
  for (int i = 254; i >= 1; --i) {
    fi[i] = fi[i + 1] + v / x[i + 1];
    long double t = -2.0L * logl(fi[i]);
    x[i] = t > 0 ? sqrtl(t) : 0.0L;
  }
  x[0] = 0.0L;
  fi[0] = 1.0L;
  z.wi[0] = (double)(v / f255 / T52);
  z.fi[0] = 1.0;
  z.ki[0] = (uint64_t)((R * f255 / v) * T52);
  z.ki[1] = 0;
  for (int i = 1; i < 256; ++i) {
    z.wi[i] = (double)(x[i] / T52);
    z.fi[i] = (double)fi[i];
  }
  for (int i = 2; i < 256; ++i)
    z.ki[i] = (uint64_t)((x[i - 1] / x[i]) * T52);
}

static double next_normal(PCG64& g, const Zig& z) {
  const double ZR = 3.6541528853610087963519472518;
  const double ZIR = 0.27366123732975827203338247596;
  for (;;) {
    uint64_t r = g.next();
    int idx = (int)(r & 0xff);
    r >>= 8;
    int sign = (int)(r & 1);
    uint64_t rabs = (r >> 1) & 0x000fffffffffffffULL;
    double x = (double)rabs * z.wi[idx];
    if (sign) x = -x;
    if (rabs < z.ki[idx]) return x;
    if (idx == 0) {
      double xx, yy;
      do {
        xx = -ZIR * log1p(-next_uniform(g));
        yy = -log1p(-next_uniform(g));
      } while (yy + yy <= xx * xx);
      return ((rabs >> 8) & 1) ? -(ZR + xx) : (ZR + xx);
    } else {
      if ((z.fi[idx - 1] - z.fi[idx]) * next_uniform(g) + z.fi[idx] <
          exp(-0.5 * x * x))
        return x;
    }
  }
}

static const int kInstr[15][3] = {{0, 0, 0}, {0, 1, 1}, {0, 2, 2}, {1, 0, 1},
                                 {1, 1, 0}, {1, 1, 1}, {1, 1, 2}, {1, 2, 1},
                                 {1, 2, 2}, {2, 0, 2}, {2, 1, 1}, {2, 1, 2},
                                 {2, 2, 0}, {2, 2, 1}, {2, 2, 2}};
static const int kCOff[15] = {0,   1,   10,  35,  44,  53,  80, 125,
                              170, 245, 270, 315, 390, 415, 490};

static void build_coeff(float* coeff) {
  Zig z;
  build_zig(z);
  PCG64 g;
  make_gen(g);
  for (int t = 0; t < 15; ++t) {
    int d1 = 2 * kInstr[t][0] + 1;
    int d2 = 2 * kInstr[t][1] + 1;
    int d3 = 2 * kInstr[t][2] + 1;
    int n = d1 * d2 * d3;
    bool mask[125];
    bool any = false;
    for (int i = 0; i < n; ++i) {
      mask[i] = next_uniform(g) < 0.3;
      any |= mask[i];
    }
    if (!any) mask[0] = true;
    float pw = (float)(1.0 / sqrt((double)(d1 * d2)));
    for (int i = 0; i < n; ++i) {
      float v = (float)next_normal(g, z);
      coeff[kCOff[t] + i] = mask[i] ? v * pw : 0.0f;
    }
  }
}

}  // namespace nprng

// ============================================================================
// b-first factorization:  bc[i,k] = sum_j b[j]*cg[i,j,k]  (once per edge,
// cooperatively across 32 lanes), then per-u: out[k] += w * sum_i a[i]*bc[i,k].
//
// bc layout in LDS (256 floats per es-half), paths grouped by l2-class so the
// j-index is compile-time (b register selected by class), each path padded to
// a 16B boundary for ds_read_b128:
//   class l2=0 (d2=1, b[0]):    p0 @0(1->4)   p3 @4(9->12)   p9 @16(25->28)
//   class l2=1 (d2=3, b[1..3]): p1 @64(3->4)  p4 @68(3->4)   p5 @72(9->12)
//                               p6 @84(15->16) p10 @100(15->16) p11 @116(25->28)
//   class l2=2 (d2=5, b[4..8]): p2 @160(5->8) p7 @168(9->12) p8 @180(15->16)
//                               p12 @196(5->8) p13 @204(15->16) p14 @220(25->28)
// Producer rounds: class0: 2 rounds x 1 term; class1: 3 x 3; class2: 3 x 5
// -> 26 coeffs per lane, preloaded once from the kernarg table (no loads in
// the steady-state loop).
// ============================================================================

struct CtvArg {
  float v[26 * 32];  // 3328 B, passed by value (kernarg) - no H2D memcpy
};
struct CoeffArg {
  float v[615];
};

// X(p, l1, d3, padbase, aoff)  -- consumption order groups classes for bc
// register-window reuse.
#define FOR_PATHS(X)    \
  X(0, 0, 1, 0, 0)      \
  X(3, 1, 3, 4, 9)      \
  X(9, 2, 5, 16, 29)    \
  X(1, 0, 3, 64, 1)     \
  X(4, 1, 1, 68, 12)    \
  X(5, 1, 3, 72, 13)    \
  X(6, 1, 5, 84, 16)    \
  X(10, 2, 3, 100, 34)  \
  X(11, 2, 5, 116, 37)  \
  X(2, 0, 5, 160, 4)    \
  X(7, 1, 3, 168, 21)   \
  X(8, 1, 5, 180, 24)   \
  X(12, 2, 1, 196, 42)  \
  X(13, 2, 3, 204, 43)  \
  X(14, 2, 5, 220, 46)

static void build_ctv(const float* h_coeff, CtvArg* ctv) {
  struct PD {
    int coff, d1, d3, padbase;
  };
  static const PD c0[] = {{0, 1, 1, 0}, {35, 3, 3, 4}, {245, 5, 5, 16}};
  static const PD c1[] = {{1, 1, 3, 64},   {44, 3, 1, 68},  {53, 3, 3, 72},
                          {80, 3, 5, 84},  {270, 5, 3, 100}, {315, 5, 5, 116}};
  static const PD c2[] = {{10, 1, 5, 160}, {125, 3, 3, 168}, {170, 3, 5, 180},
                          {390, 5, 1, 196}, {415, 5, 3, 204}, {490, 5, 5, 220}};
  const PD* cls[3] = {c0, c1, c2};
  const int ncls[3] = {3, 6, 6};
  const int rounds[3] = {2, 3, 3};
  const int cbase[3] = {0, 64, 160};
  const int qbase[3] = {0, 2, 11};
  for (int c = 0; c < 3; ++c) {
    int d2 = 2 * c + 1;
    for (int r = 0; r < rounds[c]; ++r)
      for (int t = 0; t < d2; ++t) {
        int q = qbase[c] + r * d2 + t;
        for (int lane = 0; lane < 32; ++lane) {
          int slot = cbase[c] + r * 32 + lane;
          float val = 0.0f;
          for (int pi = 0; pi < ncls[c]; ++pi) {
            const PD& pd = cls[c][pi];
            int rel = slot - pd.padbase;
            if (rel >= 0 && rel < pd.d1 * pd.d3) {
              int i = rel / pd.d3, k = rel % pd.d3;
              val = h_coeff[pd.coff + (i * d2 + t) * pd.d3 + k];
              break;
            }
          }
          ctv->v[q * 32 + lane] = val;
        }
      }
  }
}

// ============================================================================
// CSR build kernels (dst -> edge list). All scratch in d_ws.
// ============================================================================
__global__ void hist_kernel(const int* __restrict__ edst,
                            int* __restrict__ counts, int E) {
  int e = blockIdx.x * blockDim.x + threadIdx.x;
  if (e < E) atomicAdd(&counts[edst[e]], 1);
}

__global__ __launch_bounds__(1024) void scan_kernel(
    const int* __restrict__ counts, int* __restrict__ offsets, int n) {
  __shared__ int sh[1024];
  int t = threadIdx.x;
  int chunk = (n + 1023) >> 10;  // <=16
  int start = t * chunk;
  int local[16];
  int sum = 0;
#pragma unroll
  for (int i = 0; i < 16; ++i) {  // full unroll: static indices -> registers
    if (i < chunk) {
      int idx = start + i;
      int v = (idx < n) ? counts[idx] : 0;
      local[i] = sum;
      sum += v;
    }
  }
  sh[t] = sum;
  __syncthreads();
  for (int off = 1; off < 1024; off <<= 1) {
    int v = (t >= off) ? sh[t - off] : 0;
    __syncthreads();
    sh[t] += v;
    __syncthreads();
  }
  int base = (t == 0) ? 0 : sh[t - 1];
#pragma unroll
  for (int i = 0; i < 16; ++i) {
    if (i < chunk) {
      int idx = start + i;
      if (idx < n) offsets[idx] = base + local[i];
    }
  }
  if (t == 1023) offsets[n] = sh[1023];
}

__global__ void fill_kernel(const int* __restrict__ edst,
                            const int* __restrict__ offsets,
                            int* __restrict__ cursor, int* __restrict__ csr,
                            int E) {
  int e = blockIdx.x * blockDim.x + threadIdx.x;
  if (e >= E) return;
  int d = edst[e];
  int pos = atomicAdd(&cursor[d], 1);
  csr[offsets[d] + pos] = e;
}

// ============================================================================
// Main compute: wave = node; 64 lanes = 32 u x 2 es (edge parity).
// ============================================================================
template <int D1, int D3, int PB, int AOFF>
__device__ __forceinline__ void consume(const float* lbc,
                                        const float (&a)[D1], float w,
                                        float (&acc)[51]) {
  constexpr int NR = (D1 * D3 + 3) / 4;
  float fb[NR * 4];
#pragma unroll
  for (int r = 0; r < NR; ++r) {
    float4 v = *reinterpret_cast<const float4*>(lbc + PB + 4 * r);
    fb[4 * r + 0] = v.x;
    fb[4 * r + 1] = v.y;
    fb[4 * r + 2] = v.z;
    fb[4 * r + 3] = v.w;
  }
  float tmp[D3];
#pragma unroll
  for (int k = 0; k < D3; ++k) tmp[k] = a[0] * fb[k];
#pragma unroll
  for (int i = 1; i < D1; ++i)
#pragma unroll
    for (int k = 0; k < D3; ++k) tmp[k] = fmaf(a[i], fb[i * D3 + k], tmp[k]);
#pragma unroll
  for (int k = 0; k < D3; ++k) acc[AOFF + k] = fmaf(w, tmp[k], acc[AOFF + k]);
}

#define DO_CONSUME(p, l1, d3c, pb, aoff) \
  consume<2 * (l1) + 1, d3c, pb, aoff>(lbc, aa##l1, ww[p], acc);

#define DO_REDUCE(p, l1, d3c, pb, aoff)                    \
  _Pragma("unroll") for (int k = 0; k < (d3c); ++k)        \
      acc[(aoff) + k] += __shfl_xor(acc[(aoff) + k], 32, 64);

#define DO_STORE(p, l1, d3c, pb, aoff)                     \
  _Pragma("unroll") for (int k = 0; k < (d3c); ++k)        \
      O[(aoff)*32 + u * (d3c) + k] = acc[(aoff) + k];

__global__ __launch_bounds__(256) void tp_node_kernel(
    CtvArg cc, const float* __restrict__ in1, const float* __restrict__ in2,
    const float* __restrict__ weight, const int* __restrict__ esrc,
    const int* __restrict__ offsets, const int* __restrict__ csr,
    float* __restrict__ out, int N) {
  __shared__ float lds[4][2][256];
  int t = blockIdx.x * blockDim.x + threadIdx.x;
  int u = t & 31;
  int es = (t >> 5) & 1;
  int n = t >> 6;
  if (n >= N) return;
  int wv = threadIdx.x >> 6;
  float* lbc = &lds[wv][es][0];

  // Per-lane CG coefficients for the bc producer phase: loaded once.
  float ctv[26];
#pragma unroll
  for (int q = 0; q < 26; ++q) ctv[q] = cc.v[q * 32 + u];

  int beg = offsets[n];
  int end = offsets[n + 1];

  float acc[51];
#pragma unroll
  for (int k = 0; k < 51; ++k) acc[k] = 0.0f;

  for (int ii = beg + es; ii < end; ii += 2) {
    int e = csr[ii];
    int s = esrc[e];
    const float* __restrict__ A = in1 + (size_t)s * 288;
    const float* __restrict__ B = in2 + (size_t)e * 9;
    const float* __restrict__ W = weight + (size_t)e * 480 + u;

    float aa0[1], aa1[3], aa2[5];
    float b0v, bb1[3], bb2[5];
    float ww[15];
    aa0[0] = A[u];
#pragma unroll
    for (int i = 0; i < 3; ++i) aa1[i] = A[32 + u * 3 + i];
#pragma unroll
    for (int i = 0; i < 5; ++i) aa2[i] = A[128 + u * 5 + i];
    b0v = B[0];
#pragma unroll
    for (int j = 0; j < 3; ++j) bb1[j] = B[1 + j];
#pragma unroll
    for (int j = 0; j < 5; ++j) bb2[j] = B[4 + j];
#pragma unroll
    for (int p = 0; p < 15; ++p) ww[p] = W[p * 32];

    // ---- producer: bc = b (x) cg, 8 stride-1 ds_writes (imm offsets) ----
    float* wp = lbc + u;
    wp[0] = ctv[0] * b0v;
    wp[32] = ctv[1] * b0v;
#pragma unroll
    for (int r = 0; r < 3; ++r)
      wp[64 + r * 32] =
          fmaf(ctv[2 + 3 * r], bb1[0],
               fmaf(ctv[3 + 3 * r], bb1[1], ctv[4 + 3 * r] * bb1[2]));
#pragma unroll
    for (int r = 0; r < 3; ++r)
      wp[160 + r * 32] =
          fmaf(ctv[11 + 5 * r], bb2[0],
               fmaf(ctv[12 + 5 * r], bb2[1],
                    fmaf(ctv[13 + 5 * r], bb2[2],
                         fmaf(ctv[14 + 5 * r], bb2[3],
                              ctv[15 + 5 * r] * bb2[4]))));

    // Wave-internal write->read ordering: DS ops execute in order per wave;
    // fence stops the compiler from hoisting the reads above the writes.
    __builtin_amdgcn_wave_barrier();
    asm volatile("" ::: "memory");

    // ---- consumer: per-u contraction, uniform ds_read_b128 ----
    FOR_PATHS(DO_CONSUME)

    asm volatile("" ::: "memory");  // next iter's writes stay after reads
  }

  FOR_PATHS(DO_REDUCE)
  if (es == 0) {
    float* __restrict__ O = out + (size_t)n * 1632;
    FOR_PATHS(DO_STORE)
  }
}

// ============================================================================
// Fallback (atomic kernel, dense ct from ws) if ws_size too small for CSR.
// ============================================================================
#define FOR_ALL_INSTR(X)                                                   \
  X(0, 0, 0, 0, 0, 0)                                                      \
  X(1, 0, 1, 1, 1, 1)                                                      \
  X(2, 0, 2, 2, 10, 4)                                                     \
  X(3, 1, 0, 1, 35, 9)                                                     \
  X(4, 1, 1, 0, 44, 12)                                                    \
  X(5, 1, 1, 1, 53, 13)                                                    \
  X(6, 1, 1, 2, 80, 16)                                                    \
  X(7, 1, 2, 1, 125, 21)                                                   \
  X(8, 1, 2, 2, 170, 24)                                                   \
  X(9, 2, 0, 2, 245, 29)                                                   \
  X(10, 2, 1, 1, 270, 34)                                                  \
  X(11, 2, 1, 2, 315, 37)                                                  \
  X(12, 2, 2, 0, 390, 42)                                                  \
  X(13, 2, 2, 1, 415, 43)                                                  \
  X(14, 2, 2, 2, 490, 46)

template <int D1, int D2, int D3, int COFF, int AOFF>
__device__ __forceinline__ void contract(const float* __restrict__ ct,
                                         const float (&a)[D1],
                                         const float (&b)[D2],
                                         float (&acc)[51]) {
#pragma unroll
  for (int i = 0; i < D1; ++i)
#pragma unroll
    for (int j = 0; j < D2; ++j) {
      float ab = a[i] * b[j];
#pragma unroll
      for (int k = 0; k < D3; ++k)
        acc[AOFF + k] =
            fmaf(ab, ct[COFF + (i * D2 + j) * D3 + k], acc[AOFF + k]);
    }
}

#define DO_CONTRACT(idx, l1, l2, l3, coff, aoff)                       \
  contract<2 * (l1) + 1, 2 * (l2) + 1, 2 * (l3) + 1, coff, aoff>(      \
      ct, aa##l1, bb##l2, acc);

#define DO_EPI(idx, l1, l2, l3, coff, aoff)                            \
  {                                                                    \
    float wv2 = W[(idx)*32];                                           \
    _Pragma("unroll") for (int k = 0; k < 2 * (l3) + 1; ++k)           \
        atomicAdd(O + ((aoff)*32 + u * (2 * (l3) + 1) + k),            \
                  acc[(aoff) + k] * wv2);                              \
  }

__global__ __launch_bounds__(256) void tp_kernel(
    const float* __restrict__ in1, const float* __restrict__ in2,
    const float* __restrict__ weight, const int* __restrict__ esrc,
    const int* __restrict__ edst, const float* __restrict__ ct,
    float* __restrict__ out, int E) {
  int t = blockIdx.x * blockDim.x + threadIdx.x;
  int e = t >> 5;
  if (e >= E) return;
  int u = t & 31;
  int s = esrc[e];
  int d = edst[e];
  const float* __restrict__ A = in1 + (size_t)s * 288;
  const float* __restrict__ B = in2 + (size_t)e * 9;
  const float* __restrict__ W = weight + (size_t)e * 480 + u;
  float* __restrict__ O = out + (size_t)d * 1632;

  float aa0[1], aa1[3], aa2[5], bb0[1], bb1[3], bb2[5];
  aa0[0] = A[u];
#pragma unroll
  for (int i = 0; i < 3; ++i) aa1[i] = A[32 + u * 3 + i];
#pragma unroll
  for (int i = 0; i < 5; ++i) aa2[i] = A[128 + u * 5 + i];
  bb0[0] = B[0];
#pragma unroll
  for (int j = 0; j < 3; ++j) bb1[j] = B[1 + j];
#pragma unroll
  for (int j = 0; j < 5; ++j) bb2[j] = B[4 + j];

  float acc[51];
#pragma unroll
  for (int k = 0; k < 51; ++k) acc[k] = 0.0f;

  FOR_ALL_INSTR(DO_CONTRACT)
  FOR_ALL_INSTR(DO_EPI)
}

// ============================================================================

extern "C" void kernel_launch(void* const* d_in, const int* in_sizes, int n_in,
                              void* d_out, int out_size, void* d_ws,
                              size_t ws_size, hipStream_t stream) {
  static float h_coeff[615];
  static CtvArg h_ctv;
  static std::once_flag once;
  std::call_once(once, []() {
    nprng::build_coeff(h_coeff);
    build_ctv(h_coeff, &h_ctv);
    (void)hipHostRegister(h_coeff, sizeof(h_coeff), hipHostRegisterDefault);
  });

  const float* in1 = (const float*)d_in[0];
  const float* in2 = (const float*)d_in[1];
  const float* wgt = (const float*)d_in[2];
  const int* esrc = (const int*)d_in[3];
  const int* edst = (const int*)d_in[4];
  float* out = (float*)d_out;

  int N = in_sizes[0] / 288;  // 10000
  int E = in_sizes[1] / 9;    // 100000

  // ws layout (ints): [0,N) counts | [N,2N) cursor | [2N,3N+1) offsets |
  // [align16 up, +E) csr
  int* ws = (int*)d_ws;
  const int CNT_OFF = 0;
  const int CUR_OFF = CNT_OFF + N;
  const int OFF_OFF = CUR_OFF + N;
  int csr_off = OFF_OFF + N + 1;
  csr_off = (csr_off + 3) & ~3;
  size_t needed = (size_t)(csr_off + E) * 4;

  if (ws_size >= needed) {
    int* counts = ws + CNT_OFF;
    int* cursor = ws + CUR_OFF;
    int* offsets = ws + OFF_OFF;
    int* csr = ws + csr_off;

    hipMemsetAsync(counts, 0, (size_t)(2 * N) * 4, stream);
    hist_kernel<<<(E + 255) / 256, 256, 0, stream>>>(edst, counts, E);
    scan_kernel<<<1, 1024, 0, stream>>>(counts, offsets, N);
    fill_kernel<<<(E + 255) / 256, 256, 0, stream>>>(edst, offsets, cursor,
                                                     csr, E);
    int blocks = (N + 3) / 4;  // 64 threads per node
    tp_node_kernel<<<blocks, 256, 0, stream>>>(h_ctv, in1, in2, wgt, esrc,
                                               offsets, csr, out, N);
  } else if (ws_size >= sizeof(h_coeff)) {
    // Fallback: atomic path with dense ct staged in ws.
    float* ct = (float*)ws;
    hipMemcpyAsync(ct, h_coeff, sizeof(h_coeff), hipMemcpyHostToDevice,
                   stream);
    hipMemsetAsync(out, 0, (size_t)out_size * sizeof(float), stream);
    int threads = E * 32;
    tp_kernel<<<(threads + 255) / 256, 256, 0, stream>>>(in1, in2, wgt, esrc,
                                                         edst, ct, out, E);
  }
}